// Round 16
// baseline (516.220 us; speedup 1.0000x reference)
//
#include <hip/hip_runtime.h>
#include <hip/hip_bf16.h>
#include <stdint.h>

// Encoder: X -> fused(transpose+QKV GEMMs) -> attention(softmax) -> LSTM (Wx fused)
// B=512 T=128 N=256 H=256, all inputs f32, output f32 (B,T,H).
// Round 16: k_lstm11 — chain-shortening: (1) own-col h written directly to LDS
// (reload fetches only partners' 192 cols); (2) out-store deferred past the
// vmcnt drain (drain covers only the h publish); layouts/sync otherwise = R15.

#define DI __device__ __forceinline__

typedef __attribute__((ext_vector_type(8))) short bf16x8;   // 8 bf16 = 4 VGPR (MFMA A/B frag)
typedef __attribute__((ext_vector_type(4))) short short4v;  // 8B
typedef __attribute__((ext_vector_type(4))) float f32x4;    // MFMA C/D frag
typedef __attribute__((ext_vector_type(4))) int int4v;      // 16B

union U8 { bf16x8 v; short4v h[2]; int4v i; };

DI unsigned short f2bf(float x){
  union { float f; unsigned u; } v; v.f = x;
  unsigned r = v.u + 0x7fffu + ((v.u >> 16) & 1u);
  return (unsigned short)(r >> 16);
}
DI float bf2f(unsigned short x){
  union { unsigned u; float f; } v; v.u = ((unsigned)x) << 16; return v.f;
}
DI float rcp_(float x){ return __builtin_amdgcn_rcpf(x); }
DI float sigm(float x){ return rcp_(1.0f + __expf(-x)); }
DI float tanhf_(float x){ return 1.0f - 2.0f * rcp_(1.0f + __expf(2.0f * x)); }

#define BB 512
#define TT 128
#define NN 256
#define HH 256

// ---------------------------------------------------------------------------
// K0 (fused preps): bx<64: QKV weight cast + bias + flags(2048); bx<96: W_hh pack;
// else: W_ih pack.
__global__ void k_prep3(const float* __restrict__ Wq, const float* __restrict__ Wk,
                        const float* __restrict__ Wv, const float* __restrict__ Wih,
                        const float* __restrict__ Whh,
                        const float* __restrict__ bih, const float* __restrict__ bhh,
                        unsigned short* __restrict__ wqb, unsigned short* __restrict__ wkb,
                        unsigned short* __restrict__ wvb,
                        unsigned short* __restrict__ wihf, unsigned short* __restrict__ whhf,
                        float* __restrict__ bias, int* __restrict__ flags){
  int bx = blockIdx.x;
  if (bx < 64){
    int i = bx * 256 + threadIdx.x;
    wqb[i] = f2bf(Wq[i]); wkb[i] = f2bf(Wk[i]); wvb[i] = f2bf(Wv[i]);
    if (i < 1024) bias[i] = bih[i] + bhh[i];
    if (i < 2048) flags[i] = 0;
    return;
  }
  const float* W = (bx < 96) ? Whh : Wih;
  unsigned short* w_f = (bx < 96) ? whhf : wihf;
  int idx = ((bx < 96) ? (bx - 64) : (bx - 96)) * 256 + threadIdx.x;  // 8192
  int j = idx >> 3, kk = idx & 7;
  const float* src = W + j * 256 + kk * 32;
  unsigned short o[32];
  #pragma unroll
  for (int g = 0; g < 4; ++g)
    #pragma unroll
    for (int e = 0; e < 4; ++e){
      o[g * 8 + e]     = f2bf(src[4 * g + e]);
      o[g * 8 + 4 + e] = f2bf(src[16 + 4 * g + e]);
    }
  int4v* dst = (int4v*)((char*)w_f + j * 512 + kk * 64);
  #pragma unroll
  for (int q = 0; q < 4; ++q) dst[q] = *(int4v*)(o + q * 8);
}

// ---------------------------------------------------------------------------
// K2 v2: fused transpose + Q/K/V. 1024 blocks x 256 thr; block = (batch, n-half).
__global__ __launch_bounds__(256) void k_qkv2(const float* __restrict__ X,
      const unsigned short* __restrict__ Wqb, const unsigned short* __restrict__ Wkb,
      const unsigned short* __restrict__ Wvb,
      unsigned short* __restrict__ Qo, unsigned short* __restrict__ Ko,
      unsigned short* __restrict__ Vo){
  __shared__ __align__(16) char smem[98816];
  char* As2 = smem;                       // A bf16 [128 rows][256B], XOR (row&7)<<4
  float* tile = (float*)(smem + 32768);   // f32 [128][129]
  char* Bs = smem + 32768;                // W panel (overlays tile)
  char* Os = smem + 65536;                // out stage
  int bid = blockIdx.x;
  int b = bid >> 1, nh = bid & 1;
  int n0 = nh * 128;
  int m0 = b * 256 + n0;
  int tid = threadIdx.x;

  {
    int nl = tid & 127, tg = tid >> 7;
    const float* src = X + (size_t)b * TT * NN + n0 + nl;
    #pragma unroll
    for (int r = 0; r < 64; ++r){
      int t = r * 2 + tg;
      tile[t * 129 + nl] = src[(size_t)t * NN];
    }
  }
  __syncthreads();
  {
    int tpos = tid & 31, nrow = tid >> 5;
    #pragma unroll
    for (int rr = 0; rr < 16; ++rr){
      int n = rr * 8 + nrow;
      int t0 = tpos * 4;
      short4v v = { (short)f2bf(tile[(t0    ) * 129 + n]),
                    (short)f2bf(tile[(t0 + 1) * 129 + n]),
                    (short)f2bf(tile[(t0 + 2) * 129 + n]),
                    (short)f2bf(tile[(t0 + 3) * 129 + n]) };
      *(short4v*)(As2 + n * 256 + ((t0 * 2) ^ ((n & 7) << 4))) = v;
    }
  }

  int lane = tid & 63, wv = tid >> 6;
  int wr = wv >> 1, wc = wv & 1;
  int l15 = lane & 15, g = lane >> 4;
  f32x4 zro = {0.f, 0.f, 0.f, 0.f};

  #pragma unroll 1
  for (int mode = 0; mode < 3; ++mode){
    const unsigned short* W = (mode == 0) ? Wqb : ((mode == 1) ? Wkb : Wvb);
    __syncthreads();
    #pragma unroll
    for (int it = 0; it < 16; ++it){
      int c = it * 256 + tid;
      int j = c >> 5;
      int kc = (c & 31) << 2;
      short4v v = *(const short4v*)(W + j * 128 + kc);
      *(short4v*)(Bs + j * 256 + ((kc * 2) ^ ((j & 7) << 4))) = v;
    }
    __syncthreads();
    f32x4 acc[4][4];
    #pragma unroll
    for (int a = 0; a < 4; ++a)
      #pragma unroll
      for (int bq = 0; bq < 4; ++bq) acc[a][bq] = zro;
    #pragma unroll
    for (int ks = 0; ks < 4; ++ks){
      U8 af[4];
      #pragma unroll
      for (int mt = 0; mt < 4; ++mt){
        int ar = wr * 64 + mt * 16 + l15;
        const char* ab = As2 + ar * 256;
        int sw = (ar & 7) << 4;
        af[mt].h[0] = *(const short4v*)(ab + ((ks * 64 + 8 * g) ^ sw));
        af[mt].h[1] = *(const short4v*)(ab + ((ks * 64 + 8 * g + 32) ^ sw));
      }
      #pragma unroll
      for (int nt = 0; nt < 4; ++nt){
        int jr = wc * 64 + nt * 16 + l15;
        const char* bb = Bs + jr * 256;
        int kb = ks * 64 + 8 * g, sw = (jr & 7) << 4;
        U8 bf;
        bf.h[0] = *(const short4v*)(bb + (kb ^ sw));
        bf.h[1] = *(const short4v*)(bb + ((kb + 32) ^ sw));
        #pragma unroll
        for (int mt = 0; mt < 4; ++mt)
          acc[mt][nt] = __builtin_amdgcn_mfma_f32_16x16x32_bf16(af[mt].v, bf.v, acc[mt][nt], 0, 0, 0);
      }
    }
    float scale = (mode == 0) ? 0.0625f : 1.0f;
    #pragma unroll
    for (int mt = 0; mt < 4; ++mt)
      #pragma unroll
      for (int nt = 0; nt < 4; ++nt)
        #pragma unroll
        for (int r = 0; r < 4; ++r){
          int row = wr * 64 + mt * 16 + g * 4 + r;
          int col = wc * 64 + nt * 16 + l15;
          unsigned short hv = f2bf(acc[mt][nt][r] * scale);
          int addr = (mode == 2) ? (col * 256 + ((row * 2) ^ ((col & 7) << 4)))
                                 : (row * 256 + ((col * 2) ^ ((row & 7) << 4)));
          *(unsigned short*)(Os + addr) = hv;
        }
    __syncthreads();
    int orow = tid >> 1, oseg = tid & 1;
    const char* srcrow = Os + orow * 256;
    unsigned short* dst;
    if (mode == 2){
      dst = Vo + ((size_t)b * 128 + orow) * 256 + n0 + oseg * 64;
    } else {
      dst = ((mode == 0) ? Qo : Ko) + (size_t)(m0 + orow) * 128 + oseg * 64;
    }
    #pragma unroll
    for (int c = 0; c < 8; ++c){
      int kb = oseg * 128 + c * 16;
      *(int4v*)((char*)dst + c * 16) = *(const int4v*)(srcrow + (kb ^ ((orow & 7) << 4)));
    }
  }
}

// ---------------------------------------------------------------------------
// K3 v2: fused attention, i-tile 128. grid (2, 512), 512 thr (8 waves).
__global__ __launch_bounds__(512) void k_attn2(const unsigned short* __restrict__ Q,
        const unsigned short* __restrict__ K, const unsigned short* __restrict__ Vt,
        unsigned short* __restrict__ Xa){
  __shared__ __align__(16) char smem[131072 + 512];
  char* Qs = smem;                  // 128 x 256B, XOR (row&7)<<4
  char* Ks = smem + 32768;          // 256 x 256B
  char* Ps = smem;                  // 128 x 512B (phase 2)
  char* Vs = smem + 65536;          // 128 x 512B (phase 2)
  float* rden = (float*)(smem + 131072);
  int b = blockIdx.y, i0 = blockIdx.x * 128;
  int tid = threadIdx.x, lane = tid & 63, wv = tid >> 6;
  int l15 = lane & 15, g = lane >> 4;

  {
    int row = tid >> 2, q = tid & 3;
    const char* src = (const char*)(Q + ((size_t)b * 256 + i0 + row) * 128) + q * 64;
    char* dstr = Qs + row * 256;
    int sw = (row & 7) << 4;
    #pragma unroll
    for (int c = 0; c < 4; ++c){
      int kb = q * 64 + c * 16;
      *(int4v*)(dstr + (kb ^ sw)) = *(const int4v*)(src + c * 16);
    }
  }
  {
    int row = tid >> 1, half = tid & 1;
    const char* src = (const char*)(K + ((size_t)b * 256 + row) * 128) + half * 128;
    char* dstr = Ks + row * 256;
    int sw = (row & 7) << 4;
    #pragma unroll
    for (int c = 0; c < 8; ++c){
      int kb = half * 128 + c * 16;
      *(int4v*)(dstr + (kb ^ sw)) = *(const int4v*)(src + c * 16);
    }
  }
  __syncthreads();

  f32x4 zro = {0.f, 0.f, 0.f, 0.f};
  f32x4 acc[16];
  #pragma unroll
  for (int nt = 0; nt < 16; ++nt) acc[nt] = zro;
  #pragma unroll
  for (int kk = 0; kk < 4; ++kk){
    int ar = wv * 16 + l15;
    const char* ab = Qs + ar * 256;
    int kb = kk * 64 + 8 * g, swa = (ar & 7) << 4;
    U8 a;
    a.h[0] = *(const short4v*)(ab + (kb ^ swa));
    a.h[1] = *(const short4v*)(ab + ((kb + 32) ^ swa));
    #pragma unroll
    for (int nt = 0; nt < 16; ++nt){
      int jr = nt * 16 + l15;
      const char* bb = Ks + jr * 256;
      int swb = (jr & 7) << 4;
      U8 bf;
      bf.h[0] = *(const short4v*)(bb + (kb ^ swb));
      bf.h[1] = *(const short4v*)(bb + ((kb + 32) ^ swb));
      acc[nt] = __builtin_amdgcn_mfma_f32_16x16x32_bf16(a.v, bf.v, acc[nt], 0, 0, 0);
    }
  }
  float mx[4], sm[4];
  #pragma unroll
  for (int r = 0; r < 4; ++r){
    float m = acc[0][r];
    #pragma unroll
    for (int nt = 1; nt < 16; ++nt) m = fmaxf(m, acc[nt][r]);
    #pragma unroll
    for (int s = 1; s < 16; s <<= 1) m = fmaxf(m, __shfl_xor(m, s));
    mx[r] = m;
  }
  #pragma unroll
  for (int r = 0; r < 4; ++r){
    float s = 0.f;
    #pragma unroll
    for (int nt = 0; nt < 16; ++nt){
      float p = __expf(acc[nt][r] - mx[r]);
      acc[nt][r] = p; s += p;
    }
    #pragma unroll
    for (int sd = 1; sd < 16; sd <<= 1) s += __shfl_xor(s, sd);
    sm[r] = s;
  }
  __syncthreads();          // all S reads of Qs/Ks done -> safe to overlay Ps/Vs
  #pragma unroll
  for (int nt = 0; nt < 16; ++nt)
    #pragma unroll
    for (int r = 0; r < 4; ++r){
      int ir = wv * 16 + g * 4 + r;
      *(unsigned short*)(Ps + ir * 512 + ((nt * 16 + l15) * 2 ^ ((ir & 7) << 4))) = f2bf(acc[nt][r]);
    }
  #pragma unroll
  for (int r = 0; r < 4; ++r)
    if (l15 == r) rden[wv * 16 + g * 4 + r] = rcp_(sm[r]);
  {
    int row = tid >> 2, q = tid & 3;
    const char* src = (const char*)(Vt + ((size_t)b * 128 + row) * 256) + q * 128;
    char* dstr = Vs + row * 512;
    int sw = (row & 7) << 4;
    #pragma unroll
    for (int c = 0; c < 8; ++c){
      int jb = q * 128 + c * 16;
      *(int4v*)(dstr + (jb ^ sw)) = *(const int4v*)(src + c * 16);
    }
  }
  __syncthreads();

  f32x4 acc2[8];
  #pragma unroll
  for (int nt = 0; nt < 8; ++nt) acc2[nt] = zro;
  #pragma unroll
  for (int kk = 0; kk < 8; ++kk){
    int kb = kk * 64 + 8 * g;
    U8 bfr[8];
    #pragma unroll
    for (int nt = 0; nt < 8; ++nt){
      int ir = nt * 16 + l15;
      const char* pb = Ps + ir * 512;
      int sw = (ir & 7) << 4;
      bfr[nt].h[0] = *(const short4v*)(pb + (kb ^ sw));
      bfr[nt].h[1] = *(const short4v*)(pb + ((kb + 32) ^ sw));
    }
    int tr = wv * 16 + l15;
    const char* ab = Vs + tr * 512;
    int sw = (tr & 7) << 4;
    U8 a;
    a.h[0] = *(const short4v*)(ab + (kb ^ sw));
    a.h[1] = *(const short4v*)(ab + ((kb + 32) ^ sw));
    #pragma unroll
    for (int nt = 0; nt < 8; ++nt)
      acc2[nt] = __builtin_amdgcn_mfma_f32_16x16x32_bf16(a.v, bfr[nt].v, acc2[nt], 0, 0, 0);
  }
  #pragma unroll
  for (int nt = 0; nt < 8; ++nt){
    float rd = rden[nt * 16 + l15];
    #pragma unroll
    for (int r = 0; r < 4; ++r){
      int t = wv * 16 + g * 4 + r;
      int i = i0 + nt * 16 + l15;
      Xa[((size_t)b * 128 + t) * 256 + i] = f2bf(acc2[nt][r] * rd);
    }
  }
}

// ---------------------------------------------------------------------------
// K5 v11: LSTM (fused Wx). Own-col h written directly to LDS (reload = partner
// cols only); out-store deferred past the vmcnt drain. Rest = k_lstm10.
__global__ __launch_bounds__(512, 2) void k_lstm11(const unsigned short* __restrict__ Xa,
        const unsigned short* __restrict__ whh_f, const unsigned short* __restrict__ wih_f,
        const float* __restrict__ bias, float* __restrict__ out,
        unsigned int* __restrict__ hbuf, int* __restrict__ flags){
  __shared__ __align__(16) char smem[131072 + 8192 + 8192 + 8448];
  char* WI = smem;                       // W_ih slice frag-major, chunk XOR (jl&7)
  char* HS = smem + 131072;              // h frag-major: [16 rows][32 chunks^row&7][16B]
  char* XS = smem + 139264;              // Xa(t) frag-major; rows 8-15 = 0
  float* GS = (float*)(smem + 147456);   // gate stage [batch][gate][col], stride 264
  int tid = threadIdx.x, lane = tid & 63, wv = tid >> 6;
  int l15 = lane & 15, g = lane >> 4;
  int bid = blockIdx.x;
  int x = bid & 7, q = bid >> 3;             // same-XCD grouping heuristic
  int y = q >> 2, m = q & 3;
  int grp = y * 8 + x;                       // [0,64)
  int b0 = grp * 8;
  int c0 = m * 64;
  int tb = tid >> 6, tc = tid & 63;          // gate-phase (batch, col_local)
  // fragment-major scatter for 4-col chunk tc*4 (reload path)
  int f_kk = tc >> 3, f_g = tc & 3, f_hf = (tc >> 2) & 1;
  int f_off = f_hf * 8;
  // fragment-major scatter for the single own col ctx = c0 + tc (direct-HS path)
  int ctx = c0 + tc;
  int o_chunk = ((ctx >> 5) * 4 + ((ctx & 15) >> 2));
  int o_in = ((ctx >> 4) & 1) * 8 + (ctx & 3) * 2;

  U8 breg[2][8];
  #pragma unroll
  for (int nt = 0; nt < 2; ++nt){
    int jl = wv * 32 + nt * 16 + l15;
    int jg = (jl >> 6) * 256 + c0 + (jl & 63);
    #pragma unroll
    for (int kk = 0; kk < 8; ++kk)
      breg[nt][kk].i = *(const int4v*)((const char*)whh_f + (size_t)jg * 512 + kk * 64 + g * 16);
  }
  {
    int jl = tid >> 1, hq = (tid & 1) * 16;
    int jg = (jl >> 6) * 256 + c0 + (jl & 63);
    const char* src = (const char*)wih_f + (size_t)jg * 512;
    char* dst = WI + jl * 512;
    int sx = jl & 7;
    #pragma unroll
    for (int c2 = 0; c2 < 16; ++c2){
      int c = hq + c2;
      *(int4v*)(dst + ((c ^ sx) << 4)) = *(const int4v*)(src + c * 16);
    }
  }
  { int4v z = {0,0,0,0}; *(int4v*)(HS + tid * 16) = z; }
  if (tid < 256){ int4v z = {0,0,0,0}; *(int4v*)(XS + 4096 + tid * 16) = z; }
  { // XS rows 0-7 = Xa(t=0), fragment-major
    short4v v = *(const short4v*)(Xa + ((size_t)(b0 + tb) * 128) * 256 + tc * 4);
    *(short4v*)(XS + tb * 512 + (((f_kk * 4 + f_g) ^ (tb & 7)) << 4) + f_off) = v;
  }
  float bs0 = bias[      c0 + tc], bs1 = bias[256 + c0 + tc];
  float bs2 = bias[512 + c0 + tc], bs3 = bias[768 + c0 + tc];
  float cst = 0.f;
  __syncthreads();

  const char* hsrow = HS + l15 * 512;
  const char* xsrow = XS + l15 * 512;
  const char* wib0 = WI + (wv * 32 + l15) * 512;
  const char* wib1 = WI + (wv * 32 + 16 + l15) * 512;
  int sxa = l15 & 7;
  int keep = g >> 1;
  f32x4 zro = {0.f, 0.f, 0.f, 0.f};

  f32x4 accX[2] = {zro, zro};
  #pragma unroll
  for (int kk = 0; kk < 8; ++kk){
    U8 a2, w0, w1;
    int cx = ((kk * 4 + g) ^ sxa) << 4;
    a2.i = *(const int4v*)(xsrow + cx);
    w0.i = *(const int4v*)(wib0 + cx);
    w1.i = *(const int4v*)(wib1 + cx);
    accX[0] = __builtin_amdgcn_mfma_f32_16x16x32_bf16(a2.v, w0.v, accX[0], 0, 0, 0);
    accX[1] = __builtin_amdgcn_mfma_f32_16x16x32_bf16(a2.v, w1.v, accX[1], 0, 0, 0);
  }

  #pragma unroll 1
  for (int t = 0; t < 128; ++t){
    short4v xan = {0, 0, 0, 0};
    if (t < 127)
      xan = *(const short4v*)(Xa + ((size_t)(b0 + tb) * 128 + (t + 1)) * 256 + tc * 4);
    f32x4 acc[2] = {accX[0], accX[1]};
    #pragma unroll
    for (int kk = 0; kk < 8; ++kk){
      U8 a;
      a.i = *(const int4v*)(hsrow + (((kk * 4 + g) ^ sxa) << 4));
      acc[0] = __builtin_amdgcn_mfma_f32_16x16x32_bf16(a.v, breg[0][kk].v, acc[0], 0, 0, 0);
      acc[1] = __builtin_amdgcn_mfma_f32_16x16x32_bf16(a.v, breg[1][kk].v, acc[1], 0, 0, 0);
    }
    #pragma unroll
    for (int r = 0; r < 4; ++r){
      float v0 = acc[0][r], v1 = acc[1][r];
      float kv = keep ? v1 : v0;
      float sv = keep ? v0 : v1;
      float val = kv + __shfl_xor(sv, 32);
      int jl = wv * 32 + keep * 16 + l15;
      int batch = (g & 1) * 4 + r;
      GS[batch * 264 + (jl >> 6) * 66 + (jl & 63)] = val;
    }
    __syncthreads();                       // A: fold visible; XS(t)/HS(t) reads done
    float gv0 = GS[tb * 264 +   0 + tc];
    float gv1 = GS[tb * 264 +  66 + tc];
    float gv2 = GS[tb * 264 + 132 + tc];
    float gv3 = GS[tb * 264 + 198 + tc];
    float gi = sigm(gv0 + bs0);
    float gf = sigm(gv1 + bs1);
    float gg = tanhf_(gv2 + bs2);
    float go = sigm(gv3 + bs3);
    float c = gf * cst + gi * gg;
    cst = c;
    float h = go * tanhf_(c);
    if (t < 127){
      unsigned short hhi = f2bf(h);
      unsigned short hlo = f2bf(h - bf2f(hhi));
      unsigned int pk = (unsigned int)hhi | ((unsigned int)hlo << 16);
      unsigned int* hb = hbuf + ((size_t)grp * 2 + (t & 1)) * 2048;
      // publish for partners (global) FIRST so the drain covers mostly this store
      __hip_atomic_store(hb + tb * 256 + c0 + tc, pk, __ATOMIC_RELAXED, __HIP_MEMORY_SCOPE_AGENT);
      // own col directly into HS (LDS) — partners' reload never touches these cols
      { int co = (o_chunk ^ (tb & 7)) << 4;
        *(unsigned short*)(HS + tb * 512 + co + o_in) = hhi;
        *(unsigned short*)(HS + (tb + 8) * 512 + co + o_in) = hlo; }
      // stage XS = Xa(t+1)
      *(short4v*)(XS + tb * 512 + (((f_kk * 4 + f_g) ^ (tb & 7)) << 4) + f_off) = xan;
      asm volatile("s_waitcnt vmcnt(0)" ::: "memory");   // h publish at coherence pt
      if (lane == 0)
        __hip_atomic_store(&flags[grp * 32 + m * 8 + wv], t + 1,
                           __ATOMIC_RELAXED, __HIP_MEMORY_SCOPE_AGENT);
      // deferred out-store (off the drain path)
      out[((size_t)(b0 + tb) * 128 + t) * 256 + c0 + tc] = h;
      __syncthreads();                     // B: XS/own-HS visible block-wide
      // ---- accX(t+1) in the poll shadow (no h dependence)
      accX[0] = zro; accX[1] = zro;
      #pragma unroll
      for (int kk = 0; kk < 8; ++kk){
        U8 a2, w0, w1;
        int cx = ((kk * 4 + g) ^ sxa) << 4;
        a2.i = *(const int4v*)(xsrow + cx);
        w0.i = *(const int4v*)(wib0 + cx);
        w1.i = *(const int4v*)(wib1 + cx);
        accX[0] = __builtin_amdgcn_mfma_f32_16x16x32_bf16(a2.v, w0.v, accX[0], 0, 0, 0);
        accX[1] = __builtin_amdgcn_mfma_f32_16x16x32_bf16(a2.v, w1.v, accX[1], 0, 0, 0);
      }
      // ---- per-wave poll of partner wave wv's flags (lanes 1-3)
      if (lane >= 1 && lane <= 3){
        int pl = lane - 1;
        int pslot = pl + (pl >= m ? 1 : 0);
        while (__hip_atomic_load(&flags[grp * 32 + pslot * 8 + wv], __ATOMIC_RELAXED,
                                 __HIP_MEMORY_SCOPE_AGENT) <= t){}
      }
      // ---- reload PARTNER cols of h (batch row wv) into HS, fragment-major
      if ((tc >> 4) != m){
        int bb = wv, cg = tc;
        const unsigned long long* sp =
            (const unsigned long long*)(hb + bb * 256 + cg * 4);
        unsigned long long w0 = __hip_atomic_load(sp,     __ATOMIC_RELAXED, __HIP_MEMORY_SCOPE_AGENT);
        unsigned long long w1 = __hip_atomic_load(sp + 1, __ATOMIC_RELAXED, __HIP_MEMORY_SCOPE_AGENT);
        unsigned int u0 = (unsigned int)w0, u1 = (unsigned int)(w0 >> 32);
        unsigned int u2 = (unsigned int)w1, u3 = (unsigned int)(w1 >> 32);
        short4v hiv = { (short)(u0 & 0xffff), (short)(u1 & 0xffff),
                        (short)(u2 & 0xffff), (short)(u3 & 0xffff) };
        short4v lov = { (short)(u0 >> 16), (short)(u1 >> 16),
                        (short)(u2 >> 16), (short)(u3 >> 16) };
        int coff = (((f_kk * 4 + f_g) ^ (bb & 7)) << 4) + f_off;
        *(short4v*)(HS + bb * 512 + coff) = hiv;          // (bb+8)&7 == bb&7
        *(short4v*)(HS + (bb + 8) * 512 + coff) = lov;
      }
      __syncthreads();                     // D: HS ready for next matmul
    } else {
      out[((size_t)(b0 + tb) * 128 + t) * 256 + c0 + tc] = h;
    }
  }
}

// ---------------------------------------------------------------------------
extern "C" void kernel_launch(void* const* d_in, const int* in_sizes, int n_in,
                              void* d_out, int out_size, void* d_ws, size_t ws_size,
                              hipStream_t stream){
  (void)in_sizes; (void)n_in; (void)out_size; (void)ws_size;
  const float* X   = (const float*)d_in[0];
  const float* Wq  = (const float*)d_in[1];
  const float* Wk  = (const float*)d_in[2];
  const float* Wv  = (const float*)d_in[3];
  const float* Wih = (const float*)d_in[4];
  const float* Whh = (const float*)d_in[5];
  const float* bih = (const float*)d_in[6];
  const float* bhh = (const float*)d_in[7];
  float* out = (float*)d_out;
  char* ws = (char*)d_ws;

  const size_t SZ = 33554432ULL;         // one (B,*,*) bf16 buffer
  unsigned short* p_q  = (unsigned short*)ws;
  unsigned short* p_k  = (unsigned short*)(ws + SZ);
  unsigned short* p_vt = (unsigned short*)(ws + 2 * SZ);
  unsigned short* p_xa = (unsigned short*)(ws + 3 * SZ);
  char* p = ws + 4 * SZ;
  unsigned short* p_wqb = (unsigned short*)p; p += 32768;
  unsigned short* p_wkb = (unsigned short*)p; p += 32768;
  unsigned short* p_wvb = (unsigned short*)p; p += 32768;
  unsigned short* p_whhf= (unsigned short*)p; p += 524288;
  unsigned short* p_wihf= (unsigned short*)p; p += 524288;
  float* p_bias = (float*)p; p += 4096;
  unsigned int* p_hbuf = (unsigned int*)p; p += 1048576;
  int* p_flags = (int*)p;

  k_prep3<<<128, 256, 0, stream>>>(Wq, Wk, Wv, Wih, Whh, bih, bhh,
                                   p_wqb, p_wkb, p_wvb, p_wihf, p_whhf,
                                   p_bias, p_flags);
  k_qkv2<<<1024, 256, 0, stream>>>(X, p_wqb, p_wkb, p_wvb, p_q, p_k, p_vt);
  k_attn2<<<dim3(2, 512), 512, 0, stream>>>(p_q, p_k, p_vt, p_xa);
  k_lstm11<<<256, 512, 0, stream>>>(p_xa, p_whhf, p_wihf, p_bias, out, p_hbuf, p_flags);
}

// Round 17
// 500.079 us; speedup vs baseline: 1.0323x; 1.0323x over previous
//
#include <hip/hip_runtime.h>
#include <hip/hip_bf16.h>
#include <stdint.h>

// Encoder: X -> fused(transpose+QKV GEMMs) -> attention(softmax) -> LSTM (Wx fused)
// B=512 T=128 N=256 H=256, all inputs f32, output f32 (B,T,H).
// Round 17: k_lstm12 — W_ih moved LDS -> REGISTERS (wireg[2][8], +64 VGPR,
// launch_bounds(512,1) to lift the 128-VGPR cap). Cuts 16 of 32 ds_read_b128
// per wave-step (~1500 cy): the LDS-read pipe, not the sync chain, co-dominates
// the step (R14-16 sync cuts were null). LDS drops 156KB -> 25KB.

#define DI __device__ __forceinline__

typedef __attribute__((ext_vector_type(8))) short bf16x8;   // 8 bf16 = 4 VGPR (MFMA A/B frag)
typedef __attribute__((ext_vector_type(4))) short short4v;  // 8B
typedef __attribute__((ext_vector_type(4))) float f32x4;    // MFMA C/D frag
typedef __attribute__((ext_vector_type(4))) int int4v;      // 16B

union U8 { bf16x8 v; short4v h[2]; int4v i; };

DI unsigned short f2bf(float x){
  union { float f; unsigned u; } v; v.f = x;
  unsigned r = v.u + 0x7fffu + ((v.u >> 16) & 1u);
  return (unsigned short)(r >> 16);
}
DI float bf2f(unsigned short x){
  union { unsigned u; float f; } v; v.u = ((unsigned)x) << 16; return v.f;
}
DI float rcp_(float x){ return __builtin_amdgcn_rcpf(x); }
DI float sigm(float x){ return rcp_(1.0f + __expf(-x)); }
DI float tanhf_(float x){ return 1.0f - 2.0f * rcp_(1.0f + __expf(2.0f * x)); }

#define BB 512
#define TT 128
#define NN 256
#define HH 256

// ---------------------------------------------------------------------------
// K0 (fused preps): bx<64: QKV weight cast + bias + flags(2048); bx<96: W_hh pack;
// else: W_ih pack.
__global__ void k_prep3(const float* __restrict__ Wq, const float* __restrict__ Wk,
                        const float* __restrict__ Wv, const float* __restrict__ Wih,
                        const float* __restrict__ Whh,
                        const float* __restrict__ bih, const float* __restrict__ bhh,
                        unsigned short* __restrict__ wqb, unsigned short* __restrict__ wkb,
                        unsigned short* __restrict__ wvb,
                        unsigned short* __restrict__ wihf, unsigned short* __restrict__ whhf,
                        float* __restrict__ bias, int* __restrict__ flags){
  int bx = blockIdx.x;
  if (bx < 64){
    int i = bx * 256 + threadIdx.x;
    wqb[i] = f2bf(Wq[i]); wkb[i] = f2bf(Wk[i]); wvb[i] = f2bf(Wv[i]);
    if (i < 1024) bias[i] = bih[i] + bhh[i];
    if (i < 2048) flags[i] = 0;
    return;
  }
  const float* W = (bx < 96) ? Whh : Wih;
  unsigned short* w_f = (bx < 96) ? whhf : wihf;
  int idx = ((bx < 96) ? (bx - 64) : (bx - 96)) * 256 + threadIdx.x;  // 8192
  int j = idx >> 3, kk = idx & 7;
  const float* src = W + j * 256 + kk * 32;
  unsigned short o[32];
  #pragma unroll
  for (int g = 0; g < 4; ++g)
    #pragma unroll
    for (int e = 0; e < 4; ++e){
      o[g * 8 + e]     = f2bf(src[4 * g + e]);
      o[g * 8 + 4 + e] = f2bf(src[16 + 4 * g + e]);
    }
  int4v* dst = (int4v*)((char*)w_f + j * 512 + kk * 64);
  #pragma unroll
  for (int q = 0; q < 4; ++q) dst[q] = *(int4v*)(o + q * 8);
}

// ---------------------------------------------------------------------------
// K2 v2: fused transpose + Q/K/V. 1024 blocks x 256 thr; block = (batch, n-half).
__global__ __launch_bounds__(256) void k_qkv2(const float* __restrict__ X,
      const unsigned short* __restrict__ Wqb, const unsigned short* __restrict__ Wkb,
      const unsigned short* __restrict__ Wvb,
      unsigned short* __restrict__ Qo, unsigned short* __restrict__ Ko,
      unsigned short* __restrict__ Vo){
  __shared__ __align__(16) char smem[98816];
  char* As2 = smem;                       // A bf16 [128 rows][256B], XOR (row&7)<<4
  float* tile = (float*)(smem + 32768);   // f32 [128][129]
  char* Bs = smem + 32768;                // W panel (overlays tile)
  char* Os = smem + 65536;                // out stage
  int bid = blockIdx.x;
  int b = bid >> 1, nh = bid & 1;
  int n0 = nh * 128;
  int m0 = b * 256 + n0;
  int tid = threadIdx.x;

  {
    int nl = tid & 127, tg = tid >> 7;
    const float* src = X + (size_t)b * TT * NN + n0 + nl;
    #pragma unroll
    for (int r = 0; r < 64; ++r){
      int t = r * 2 + tg;
      tile[t * 129 + nl] = src[(size_t)t * NN];
    }
  }
  __syncthreads();
  {
    int tpos = tid & 31, nrow = tid >> 5;
    #pragma unroll
    for (int rr = 0; rr < 16; ++rr){
      int n = rr * 8 + nrow;
      int t0 = tpos * 4;
      short4v v = { (short)f2bf(tile[(t0    ) * 129 + n]),
                    (short)f2bf(tile[(t0 + 1) * 129 + n]),
                    (short)f2bf(tile[(t0 + 2) * 129 + n]),
                    (short)f2bf(tile[(t0 + 3) * 129 + n]) };
      *(short4v*)(As2 + n * 256 + ((t0 * 2) ^ ((n & 7) << 4))) = v;
    }
  }

  int lane = tid & 63, wv = tid >> 6;
  int wr = wv >> 1, wc = wv & 1;
  int l15 = lane & 15, g = lane >> 4;
  f32x4 zro = {0.f, 0.f, 0.f, 0.f};

  #pragma unroll 1
  for (int mode = 0; mode < 3; ++mode){
    const unsigned short* W = (mode == 0) ? Wqb : ((mode == 1) ? Wkb : Wvb);
    __syncthreads();
    #pragma unroll
    for (int it = 0; it < 16; ++it){
      int c = it * 256 + tid;
      int j = c >> 5;
      int kc = (c & 31) << 2;
      short4v v = *(const short4v*)(W + j * 128 + kc);
      *(short4v*)(Bs + j * 256 + ((kc * 2) ^ ((j & 7) << 4))) = v;
    }
    __syncthreads();
    f32x4 acc[4][4];
    #pragma unroll
    for (int a = 0; a < 4; ++a)
      #pragma unroll
      for (int bq = 0; bq < 4; ++bq) acc[a][bq] = zro;
    #pragma unroll
    for (int ks = 0; ks < 4; ++ks){
      U8 af[4];
      #pragma unroll
      for (int mt = 0; mt < 4; ++mt){
        int ar = wr * 64 + mt * 16 + l15;
        const char* ab = As2 + ar * 256;
        int sw = (ar & 7) << 4;
        af[mt].h[0] = *(const short4v*)(ab + ((ks * 64 + 8 * g) ^ sw));
        af[mt].h[1] = *(const short4v*)(ab + ((ks * 64 + 8 * g + 32) ^ sw));
      }
      #pragma unroll
      for (int nt = 0; nt < 4; ++nt){
        int jr = wc * 64 + nt * 16 + l15;
        const char* bb = Bs + jr * 256;
        int kb = ks * 64 + 8 * g, sw = (jr & 7) << 4;
        U8 bf;
        bf.h[0] = *(const short4v*)(bb + (kb ^ sw));
        bf.h[1] = *(const short4v*)(bb + ((kb + 32) ^ sw));
        #pragma unroll
        for (int mt = 0; mt < 4; ++mt)
          acc[mt][nt] = __builtin_amdgcn_mfma_f32_16x16x32_bf16(af[mt].v, bf.v, acc[mt][nt], 0, 0, 0);
      }
    }
    float scale = (mode == 0) ? 0.0625f : 1.0f;
    #pragma unroll
    for (int mt = 0; mt < 4; ++mt)
      #pragma unroll
      for (int nt = 0; nt < 4; ++nt)
        #pragma unroll
        for (int r = 0; r < 4; ++r){
          int row = wr * 64 + mt * 16 + g * 4 + r;
          int col = wc * 64 + nt * 16 + l15;
          unsigned short hv = f2bf(acc[mt][nt][r] * scale);
          int addr = (mode == 2) ? (col * 256 + ((row * 2) ^ ((col & 7) << 4)))
                                 : (row * 256 + ((col * 2) ^ ((row & 7) << 4)));
          *(unsigned short*)(Os + addr) = hv;
        }
    __syncthreads();
    int orow = tid >> 1, oseg = tid & 1;
    const char* srcrow = Os + orow * 256;
    unsigned short* dst;
    if (mode == 2){
      dst = Vo + ((size_t)b * 128 + orow) * 256 + n0 + oseg * 64;
    } else {
      dst = ((mode == 0) ? Qo : Ko) + (size_t)(m0 + orow) * 128 + oseg * 64;
    }
    #pragma unroll
    for (int c = 0; c < 8; ++c){
      int kb = oseg * 128 + c * 16;
      *(int4v*)((char*)dst + c * 16) = *(const int4v*)(srcrow + (kb ^ ((orow & 7) << 4)));
    }
  }
}

// ---------------------------------------------------------------------------
// K3 v2: fused attention, i-tile 128. grid (2, 512), 512 thr (8 waves).
__global__ __launch_bounds__(512) void k_attn2(const unsigned short* __restrict__ Q,
        const unsigned short* __restrict__ K, const unsigned short* __restrict__ Vt,
        unsigned short* __restrict__ Xa){
  __shared__ __align__(16) char smem[131072 + 512];
  char* Qs = smem;                  // 128 x 256B, XOR (row&7)<<4
  char* Ks = smem + 32768;          // 256 x 256B
  char* Ps = smem;                  // 128 x 512B (phase 2)
  char* Vs = smem + 65536;          // 128 x 512B (phase 2)
  float* rden = (float*)(smem + 131072);
  int b = blockIdx.y, i0 = blockIdx.x * 128;
  int tid = threadIdx.x, lane = tid & 63, wv = tid >> 6;
  int l15 = lane & 15, g = lane >> 4;

  {
    int row = tid >> 2, q = tid & 3;
    const char* src = (const char*)(Q + ((size_t)b * 256 + i0 + row) * 128) + q * 64;
    char* dstr = Qs + row * 256;
    int sw = (row & 7) << 4;
    #pragma unroll
    for (int c = 0; c < 4; ++c){
      int kb = q * 64 + c * 16;
      *(int4v*)(dstr + (kb ^ sw)) = *(const int4v*)(src + c * 16);
    }
  }
  {
    int row = tid >> 1, half = tid & 1;
    const char* src = (const char*)(K + ((size_t)b * 256 + row) * 128) + half * 128;
    char* dstr = Ks + row * 256;
    int sw = (row & 7) << 4;
    #pragma unroll
    for (int c = 0; c < 8; ++c){
      int kb = half * 128 + c * 16;
      *(int4v*)(dstr + (kb ^ sw)) = *(const int4v*)(src + c * 16);
    }
  }
  __syncthreads();

  f32x4 zro = {0.f, 0.f, 0.f, 0.f};
  f32x4 acc[16];
  #pragma unroll
  for (int nt = 0; nt < 16; ++nt) acc[nt] = zro;
  #pragma unroll
  for (int kk = 0; kk < 4; ++kk){
    int ar = wv * 16 + l15;
    const char* ab = Qs + ar * 256;
    int kb = kk * 64 + 8 * g, swa = (ar & 7) << 4;
    U8 a;
    a.h[0] = *(const short4v*)(ab + (kb ^ swa));
    a.h[1] = *(const short4v*)(ab + ((kb + 32) ^ swa));
    #pragma unroll
    for (int nt = 0; nt < 16; ++nt){
      int jr = nt * 16 + l15;
      const char* bb = Ks + jr * 256;
      int swb = (jr & 7) << 4;
      U8 bf;
      bf.h[0] = *(const short4v*)(bb + (kb ^ swb));
      bf.h[1] = *(const short4v*)(bb + ((kb + 32) ^ swb));
      acc[nt] = __builtin_amdgcn_mfma_f32_16x16x32_bf16(a.v, bf.v, acc[nt], 0, 0, 0);
    }
  }
  float mx[4], sm[4];
  #pragma unroll
  for (int r = 0; r < 4; ++r){
    float m = acc[0][r];
    #pragma unroll
    for (int nt = 1; nt < 16; ++nt) m = fmaxf(m, acc[nt][r]);
    #pragma unroll
    for (int s = 1; s < 16; s <<= 1) m = fmaxf(m, __shfl_xor(m, s));
    mx[r] = m;
  }
  #pragma unroll
  for (int r = 0; r < 4; ++r){
    float s = 0.f;
    #pragma unroll
    for (int nt = 0; nt < 16; ++nt){
      float p = __expf(acc[nt][r] - mx[r]);
      acc[nt][r] = p; s += p;
    }
    #pragma unroll
    for (int sd = 1; sd < 16; sd <<= 1) s += __shfl_xor(s, sd);
    sm[r] = s;
  }
  __syncthreads();          // all S reads of Qs/Ks done -> safe to overlay Ps/Vs
  #pragma unroll
  for (int nt = 0; nt < 16; ++nt)
    #pragma unroll
    for (int r = 0; r < 4; ++r){
      int ir = wv * 16 + g * 4 + r;
      *(unsigned short*)(Ps + ir * 512 + ((nt * 16 + l15) * 2 ^ ((ir & 7) << 4))) = f2bf(acc[nt][r]);
    }
  #pragma unroll
  for (int r = 0; r < 4; ++r)
    if (l15 == r) rden[wv * 16 + g * 4 + r] = rcp_(sm[r]);
  {
    int row = tid >> 2, q = tid & 3;
    const char* src = (const char*)(Vt + ((size_t)b * 128 + row) * 256) + q * 128;
    char* dstr = Vs + row * 512;
    int sw = (row & 7) << 4;
    #pragma unroll
    for (int c = 0; c < 8; ++c){
      int jb = q * 128 + c * 16;
      *(int4v*)(dstr + (jb ^ sw)) = *(const int4v*)(src + c * 16);
    }
  }
  __syncthreads();

  f32x4 acc2[8];
  #pragma unroll
  for (int nt = 0; nt < 8; ++nt) acc2[nt] = zro;
  #pragma unroll
  for (int kk = 0; kk < 8; ++kk){
    int kb = kk * 64 + 8 * g;
    U8 bfr[8];
    #pragma unroll
    for (int nt = 0; nt < 8; ++nt){
      int ir = nt * 16 + l15;
      const char* pb = Ps + ir * 512;
      int sw = (ir & 7) << 4;
      bfr[nt].h[0] = *(const short4v*)(pb + (kb ^ sw));
      bfr[nt].h[1] = *(const short4v*)(pb + ((kb + 32) ^ sw));
    }
    int tr = wv * 16 + l15;
    const char* ab = Vs + tr * 512;
    int sw = (tr & 7) << 4;
    U8 a;
    a.h[0] = *(const short4v*)(ab + (kb ^ sw));
    a.h[1] = *(const short4v*)(ab + ((kb + 32) ^ sw));
    #pragma unroll
    for (int nt = 0; nt < 8; ++nt)
      acc2[nt] = __builtin_amdgcn_mfma_f32_16x16x32_bf16(a.v, bfr[nt].v, acc2[nt], 0, 0, 0);
  }
  #pragma unroll
  for (int nt = 0; nt < 8; ++nt){
    float rd = rden[nt * 16 + l15];
    #pragma unroll
    for (int r = 0; r < 4; ++r){
      int t = wv * 16 + g * 4 + r;
      int i = i0 + nt * 16 + l15;
      Xa[((size_t)b * 128 + t) * 256 + i] = f2bf(acc2[nt][r] * rd);
    }
  }
}

// ---------------------------------------------------------------------------
// K5 v12: LSTM (fused Wx). W_ih in REGISTERS (wireg[2][8]); LDS = HS+XS+GS only.
// Own-col h direct to LDS; out-store deferred; per-wave flags+poll. = R16 otherwise.
__global__ __launch_bounds__(512, 1) void k_lstm12(const unsigned short* __restrict__ Xa,
        const unsigned short* __restrict__ whh_f, const unsigned short* __restrict__ wih_f,
        const float* __restrict__ bias, float* __restrict__ out,
        unsigned int* __restrict__ hbuf, int* __restrict__ flags){
  __shared__ __align__(16) char smem[8192 + 8192 + 8448];
  char* HS = smem;                       // h frag-major: [16 rows][32 chunks^row&7][16B]
  char* XS = smem + 8192;                // Xa(t) frag-major; rows 8-15 = 0
  float* GS = (float*)(smem + 16384);    // gate stage [batch][gate][col], stride 264
  int tid = threadIdx.x, lane = tid & 63, wv = tid >> 6;
  int l15 = lane & 15, g = lane >> 4;
  int bid = blockIdx.x;
  int x = bid & 7, q = bid >> 3;             // same-XCD grouping heuristic
  int y = q >> 2, m = q & 3;
  int grp = y * 8 + x;                       // [0,64)
  int b0 = grp * 8;
  int c0 = m * 64;
  int tb = tid >> 6, tc = tid & 63;          // gate-phase (batch, col_local)
  // fragment-major scatter for 4-col chunk tc*4 (reload path)
  int f_kk = tc >> 3, f_g = tc & 3, f_hf = (tc >> 2) & 1;
  int f_off = f_hf * 8;
  // fragment-major scatter for the single own col ctx = c0 + tc (direct-HS path)
  int ctx = c0 + tc;
  int o_chunk = ((ctx >> 5) * 4 + ((ctx & 15) >> 2));
  int o_in = ((ctx >> 4) & 1) * 8 + (ctx & 3) * 2;

  U8 breg[2][8], wireg[2][8];
  #pragma unroll
  for (int nt = 0; nt < 2; ++nt){
    int jl = wv * 32 + nt * 16 + l15;
    int jg = (jl >> 6) * 256 + c0 + (jl & 63);
    #pragma unroll
    for (int kk = 0; kk < 8; ++kk){
      breg[nt][kk].i  = *(const int4v*)((const char*)whh_f + (size_t)jg * 512 + kk * 64 + g * 16);
      wireg[nt][kk].i = *(const int4v*)((const char*)wih_f + (size_t)jg * 512 + kk * 64 + g * 16);
    }
  }
  { int4v z = {0,0,0,0}; *(int4v*)(HS + tid * 16) = z; }
  if (tid < 256){ int4v z = {0,0,0,0}; *(int4v*)(XS + 4096 + tid * 16) = z; }
  { // XS rows 0-7 = Xa(t=0), fragment-major
    short4v v = *(const short4v*)(Xa + ((size_t)(b0 + tb) * 128) * 256 + tc * 4);
    *(short4v*)(XS + tb * 512 + (((f_kk * 4 + f_g) ^ (tb & 7)) << 4) + f_off) = v;
  }
  float bs0 = bias[      c0 + tc], bs1 = bias[256 + c0 + tc];
  float bs2 = bias[512 + c0 + tc], bs3 = bias[768 + c0 + tc];
  float cst = 0.f;
  __syncthreads();

  const char* hsrow = HS + l15 * 512;
  const char* xsrow = XS + l15 * 512;
  int sxa = l15 & 7;
  int keep = g >> 1;
  f32x4 zro = {0.f, 0.f, 0.f, 0.f};

  f32x4 accX[2] = {zro, zro};
  #pragma unroll
  for (int kk = 0; kk < 8; ++kk){
    U8 a2;
    a2.i = *(const int4v*)(xsrow + (((kk * 4 + g) ^ sxa) << 4));
    accX[0] = __builtin_amdgcn_mfma_f32_16x16x32_bf16(a2.v, wireg[0][kk].v, accX[0], 0, 0, 0);
    accX[1] = __builtin_amdgcn_mfma_f32_16x16x32_bf16(a2.v, wireg[1][kk].v, accX[1], 0, 0, 0);
  }

  #pragma unroll 1
  for (int t = 0; t < 128; ++t){
    short4v xan = {0, 0, 0, 0};
    if (t < 127)
      xan = *(const short4v*)(Xa + ((size_t)(b0 + tb) * 128 + (t + 1)) * 256 + tc * 4);
    f32x4 acc[2] = {accX[0], accX[1]};
    #pragma unroll
    for (int kk = 0; kk < 8; ++kk){
      U8 a;
      a.i = *(const int4v*)(hsrow + (((kk * 4 + g) ^ sxa) << 4));
      acc[0] = __builtin_amdgcn_mfma_f32_16x16x32_bf16(a.v, breg[0][kk].v, acc[0], 0, 0, 0);
      acc[1] = __builtin_amdgcn_mfma_f32_16x16x32_bf16(a.v, breg[1][kk].v, acc[1], 0, 0, 0);
    }
    #pragma unroll
    for (int r = 0; r < 4; ++r){
      float v0 = acc[0][r], v1 = acc[1][r];
      float kv = keep ? v1 : v0;
      float sv = keep ? v0 : v1;
      float val = kv + __shfl_xor(sv, 32);
      int jl = wv * 32 + keep * 16 + l15;
      int batch = (g & 1) * 4 + r;
      GS[batch * 264 + (jl >> 6) * 66 + (jl & 63)] = val;
    }
    __syncthreads();                       // A: fold visible; XS(t)/HS(t) reads done
    float gv0 = GS[tb * 264 +   0 + tc];
    float gv1 = GS[tb * 264 +  66 + tc];
    float gv2 = GS[tb * 264 + 132 + tc];
    float gv3 = GS[tb * 264 + 198 + tc];
    float gi = sigm(gv0 + bs0);
    float gf = sigm(gv1 + bs1);
    float gg = tanhf_(gv2 + bs2);
    float go = sigm(gv3 + bs3);
    float c = gf * cst + gi * gg;
    cst = c;
    float h = go * tanhf_(c);
    if (t < 127){
      unsigned short hhi = f2bf(h);
      unsigned short hlo = f2bf(h - bf2f(hhi));
      unsigned int pk = (unsigned int)hhi | ((unsigned int)hlo << 16);
      unsigned int* hb = hbuf + ((size_t)grp * 2 + (t & 1)) * 2048;
      // publish for partners (global) FIRST so the drain covers mostly this store
      __hip_atomic_store(hb + tb * 256 + c0 + tc, pk, __ATOMIC_RELAXED, __HIP_MEMORY_SCOPE_AGENT);
      // own col directly into HS (LDS)
      { int co = (o_chunk ^ (tb & 7)) << 4;
        *(unsigned short*)(HS + tb * 512 + co + o_in) = hhi;
        *(unsigned short*)(HS + (tb + 8) * 512 + co + o_in) = hlo; }
      // stage XS = Xa(t+1)
      *(short4v*)(XS + tb * 512 + (((f_kk * 4 + f_g) ^ (tb & 7)) << 4) + f_off) = xan;
      asm volatile("s_waitcnt vmcnt(0)" ::: "memory");   // h publish at coherence pt
      if (lane == 0)
        __hip_atomic_store(&flags[grp * 32 + m * 8 + wv], t + 1,
                           __ATOMIC_RELAXED, __HIP_MEMORY_SCOPE_AGENT);
      // deferred out-store (off the drain path)
      out[((size_t)(b0 + tb) * 128 + t) * 256 + c0 + tc] = h;
      __syncthreads();                     // B: XS/own-HS visible block-wide
      // ---- accX(t+1) in the poll shadow (no h dependence)
      accX[0] = zro; accX[1] = zro;
      #pragma unroll
      for (int kk = 0; kk < 8; ++kk){
        U8 a2;
        a2.i = *(const int4v*)(xsrow + (((kk * 4 + g) ^ sxa) << 4));
        accX[0] = __builtin_amdgcn_mfma_f32_16x16x32_bf16(a2.v, wireg[0][kk].v, accX[0], 0, 0, 0);
        accX[1] = __builtin_amdgcn_mfma_f32_16x16x32_bf16(a2.v, wireg[1][kk].v, accX[1], 0, 0, 0);
      }
      // ---- per-wave poll of partner wave wv's flags (lanes 1-3)
      if (lane >= 1 && lane <= 3){
        int pl = lane - 1;
        int pslot = pl + (pl >= m ? 1 : 0);
        while (__hip_atomic_load(&flags[grp * 32 + pslot * 8 + wv], __ATOMIC_RELAXED,
                                 __HIP_MEMORY_SCOPE_AGENT) <= t){}
      }
      // ---- reload PARTNER cols of h (batch row wv) into HS, fragment-major
      if ((tc >> 4) != m){
        int bb = wv, cg = tc;
        const unsigned long long* sp =
            (const unsigned long long*)(hb + bb * 256 + cg * 4);
        unsigned long long w0 = __hip_atomic_load(sp,     __ATOMIC_RELAXED, __HIP_MEMORY_SCOPE_AGENT);
        unsigned long long w1 = __hip_atomic_load(sp + 1, __ATOMIC_RELAXED, __HIP_MEMORY_SCOPE_AGENT);
        unsigned int u0 = (unsigned int)w0, u1 = (unsigned int)(w0 >> 32);
        unsigned int u2 = (unsigned int)w1, u3 = (unsigned int)(w1 >> 32);
        short4v hiv = { (short)(u0 & 0xffff), (short)(u1 & 0xffff),
                        (short)(u2 & 0xffff), (short)(u3 & 0xffff) };
        short4v lov = { (short)(u0 >> 16), (short)(u1 >> 16),
                        (short)(u2 >> 16), (short)(u3 >> 16) };
        int coff = (((f_kk * 4 + f_g) ^ (bb & 7)) << 4) + f_off;
        *(short4v*)(HS + bb * 512 + coff) = hiv;          // (bb+8)&7 == bb&7
        *(short4v*)(HS + (bb + 8) * 512 + coff) = lov;
      }
      __syncthreads();                     // D: HS ready for next matmul
    } else {
      out[((size_t)(b0 + tb) * 128 + t) * 256 + c0 + tc] = h;
    }
  }
}

// ---------------------------------------------------------------------------
extern "C" void kernel_launch(void* const* d_in, const int* in_sizes, int n_in,
                              void* d_out, int out_size, void* d_ws, size_t ws_size,
                              hipStream_t stream){
  (void)in_sizes; (void)n_in; (void)out_size; (void)ws_size;
  const float* X   = (const float*)d_in[0];
  const float* Wq  = (const float*)d_in[1];
  const float* Wk  = (const float*)d_in[2];
  const float* Wv  = (const float*)d_in[3];
  const float* Wih = (const float*)d_in[4];
  const float* Whh = (const float*)d_in[5];
  const float* bih = (const float*)d_in[6];
  const float* bhh = (const float*)d_in[7];
  float* out = (float*)d_out;
  char* ws = (char*)d_ws;

  const size_t SZ = 33554432ULL;         // one (B,*,*) bf16 buffer
  unsigned short* p_q  = (unsigned short*)ws;
  unsigned short* p_k  = (unsigned short*)(ws + SZ);
  unsigned short* p_vt = (unsigned short*)(ws + 2 * SZ);
  unsigned short* p_xa = (unsigned short*)(ws + 3 * SZ);
  char* p = ws + 4 * SZ;
  unsigned short* p_wqb = (unsigned short*)p; p += 32768;
  unsigned short* p_wkb = (unsigned short*)p; p += 32768;
  unsigned short* p_wvb = (unsigned short*)p; p += 32768;
  unsigned short* p_whhf= (unsigned short*)p; p += 524288;
  unsigned short* p_wihf= (unsigned short*)p; p += 524288;
  float* p_bias = (float*)p; p += 4096;
  unsigned int* p_hbuf = (unsigned int*)p; p += 1048576;
  int* p_flags = (int*)p;

  k_prep3<<<128, 256, 0, stream>>>(Wq, Wk, Wv, Wih, Whh, bih, bhh,
                                   p_wqb, p_wkb, p_wvb, p_wihf, p_whhf,
                                   p_bias, p_flags);
  k_qkv2<<<1024, 256, 0, stream>>>(X, p_wqb, p_wkb, p_wvb, p_q, p_k, p_vt);
  k_attn2<<<dim3(2, 512), 512, 0, stream>>>(p_q, p_k, p_vt, p_xa);
  k_lstm12<<<256, 512, 0, stream>>>(p_xa, p_whhf, p_wihf, p_bias, out, p_hbuf, p_flags);
}